// Round 10
// baseline (190.433 us; speedup 1.0000x reference)
//
#include <hip/hip_runtime.h>
#include <math.h>

#define NIMG 32
#define NB3  771             // 257 rings * 3 sums
#define NSLICE (NIMG * 8)    // fallback: 8 shared slices per image
#define PI_F 3.14159265358979323846f

// ---------------------------------------------------------------------------
__device__ __forceinline__ float2 cadd(float2 a, float2 b){ return make_float2(a.x+b.x, a.y+b.y); }
__device__ __forceinline__ float2 csub(float2 a, float2 b){ return make_float2(a.x-b.x, a.y-b.y); }
__device__ __forceinline__ float2 cmul(float2 a, float2 b){ return make_float2(a.x*b.x - a.y*b.y, a.x*b.y + a.y*b.x); }
__device__ __forceinline__ float2 cmul_mi(float2 a){ return make_float2(a.y, -a.x); }   // * (-i)
__device__ __forceinline__ float2 tw(const float2* T, int m){ return T[m + (m >> 3)]; }
__device__ __forceinline__ int   sw(int pos){ return pos + (pos >> 3); }     // LDS pad swizzle

// 8-point DFT (DIF, natural-order outputs), e^{-2pi i/8} convention
__device__ __forceinline__ void dft8(float2* x) {
    const float c = 0.70710678118654752f;
    float2 u0 = cadd(x[0], x[4]), u1 = cadd(x[1], x[5]);
    float2 u2 = cadd(x[2], x[6]), u3 = cadd(x[3], x[7]);
    float2 v0 = csub(x[0], x[4]);
    float2 d1 = csub(x[1], x[5]);
    float2 v1 = make_float2(c*(d1.x + d1.y), c*(d1.y - d1.x));
    float2 d2 = csub(x[2], x[6]);
    float2 v2 = make_float2(d2.y, -d2.x);
    float2 d3 = csub(x[3], x[7]);
    float2 v3 = make_float2(-c*(d3.x - d3.y), -c*(d3.x + d3.y));
    float2 e0 = cadd(u0,u2), e1 = cadd(u1,u3);
    float2 f0 = csub(u0,u2), f1 = cmul_mi(csub(u1,u3));
    float2 g0 = cadd(v0,v2), g1 = cadd(v1,v3);
    float2 h0 = csub(v0,v2), h1 = cmul_mi(csub(v1,v3));
    x[0] = cadd(e0,e1); x[4] = csub(e0,e1);
    x[2] = cadd(f0,f1); x[6] = csub(f0,f1);
    x[1] = cadd(g0,g1); x[5] = csub(g0,g1);
    x[3] = cadd(h0,h1); x[7] = csub(h0,h1);
}

// ---------------------------------------------------------------------------
// DUAL per-wave 512-pt radix-8 DIF FFT: two independent chains interleaved,
// sharing one 576-slot wave-private scratch (in-order LDS pipe makes the
// readA-before-writeB overlap safe). Thread J enters with X[q] = x[J+64q],
// exits with X[k] = F(64k + r), r = 8*(J&7) + (J>>3).
// ---------------------------------------------------------------------------
__device__ __forceinline__ void wave_fft512_dual(float2* Xa, float2* Xb,
                                                 float2* Sw, const float2* T,
                                                 int J) {
    dft8(Xa);
    dft8(Xb);
#pragma unroll
    for (int k = 1; k < 8; ++k) Xa[k] = cmul(Xa[k], tw(T, J * k));
#pragma unroll
    for (int k = 1; k < 8; ++k) Xb[k] = cmul(Xb[k], tw(T, J * k));
    const int jj = J + (J >> 3);
    const int j2 = J & 7;
    const int bb = 72 * (J >> 3) + j2;

#pragma unroll
    for (int k = 0; k < 8; ++k) Sw[jj + 72*k] = Xa[k];
#pragma unroll
    for (int q = 0; q < 8; ++q) Xa[q] = Sw[bb + 9*q];
#pragma unroll
    for (int k = 0; k < 8; ++k) Sw[jj + 72*k] = Xb[k];
#pragma unroll
    for (int q = 0; q < 8; ++q) Xb[q] = Sw[bb + 9*q];

    dft8(Xa);
    dft8(Xb);
#pragma unroll
    for (int k = 1; k < 8; ++k) Xa[k] = cmul(Xa[k], tw(T, 8 * j2 * k));
#pragma unroll
    for (int k = 1; k < 8; ++k) Xb[k] = cmul(Xb[k], tw(T, 8 * j2 * k));

#pragma unroll
    for (int k = 0; k < 8; ++k) Sw[bb + 9*k] = Xa[k];
#pragma unroll
    for (int q = 0; q < 8; ++q) Xa[q] = Sw[9*J + q];
#pragma unroll
    for (int k = 0; k < 8; ++k) Sw[bb + 9*k] = Xb[k];
#pragma unroll
    for (int q = 0; q < 8; ++q) Xb[q] = Sw[9*J + q];

    dft8(Xa);
    dft8(Xb);
}

// ---------------------------------------------------------------------------
// Row pass (r5 structure, unchanged): 512 threads / 16 image-rows per block,
// Zt[im][kx][y], ONE contiguous 128 B line per thread. Zeroes out[0] (block
// 0 — race-free vs finalize: stream-ordered) and, in the !big fallback, the
// shared slices.
// ---------------------------------------------------------------------------
__global__ __launch_bounds__(512) void fft_rows_T(const float* __restrict__ xr,
                                                  const float* __restrict__ yr,
                                                  float2* __restrict__ Zt,
                                                  float* __restrict__ sums,
                                                  float* __restrict__ out,
                                                  int big) {
    __shared__ float2 S[8 * 576];      // 36,864 B (wave scratch + park)
    __shared__ float2 T[576];          //  4,608 B
    const int t = threadIdx.x, w = t >> 6, J = t & 63;
    const int im = blockIdx.x >> 5, grp = blockIdx.x & 31;   // 32 imgs x 32 grps

    if (!big && blockIdx.x < NSLICE) {
        float* z = sums + (size_t)blockIdx.x * NB3;
        for (int i = t; i < NB3; i += 512) z[i] = 0.0f;
    }
    if (blockIdx.x == 0 && t == 0) out[0] = 0.0f;

    {
        float s, c;
        __sincosf(-2.0f * PI_F * (float)t / 512.0f, &s, &c);
        T[t + (t >> 3)] = make_float2(c, s);
    }

    // wave w: rowA = grp*16 + w, rowB = grp*16 + 8 + w
    const size_t b0 = ((size_t)(im * 512 + grp * 16 + w)) << 9;
    const size_t b1 = b0 + ((size_t)8 << 9);
    float2 X0[8], X1[8];
#pragma unroll
    for (int q = 0; q < 8; ++q) {
        X0[q] = make_float2(xr[b0 + J + 64*q], yr[b0 + J + 64*q]);
        X1[q] = make_float2(xr[b1 + J + 64*q], yr[b1 + J + 64*q]);
    }
    __syncthreads();                       // T ready

    float2* Sw = S + w * 576;
    wave_fft512_dual(X0, X1, Sw, T, J);

    const int r = ((J & 7) << 3) | (J >> 3);

    // park X0 (rows y0..y0+7, one per wave) -> gather 8 y's per kx
#pragma unroll
    for (int k = 0; k < 8; ++k) Sw[64*k + r] = X0[k];
    __syncthreads();
    float2 eA[8];
#pragma unroll
    for (int j = 0; j < 8; ++j) eA[j] = S[j*576 + t];   // F_row(y0+j)(kx=t)
    __syncthreads();

    // park X1 (rows y0+8..y0+15)
#pragma unroll
    for (int k = 0; k < 8; ++k) Sw[64*k + r] = X1[k];
    __syncthreads();
    float2 eB[8];
#pragma unroll
    for (int j = 0; j < 8; ++j) eB[j] = S[j*576 + t];   // F_row(y0+8+j)(kx=t)

    // one full 128 B line per thread: Zt[im][t][grp*16 .. grp*16+15]
    float4* o = (float4*)(Zt + ((size_t)im << 18) + ((size_t)t << 9)
                             + (size_t)(grp * 16));
    o[0] = make_float4(eA[0].x, eA[0].y, eA[1].x, eA[1].y);
    o[1] = make_float4(eA[2].x, eA[2].y, eA[3].x, eA[3].y);
    o[2] = make_float4(eA[4].x, eA[4].y, eA[5].x, eA[5].y);
    o[3] = make_float4(eA[6].x, eA[6].y, eA[7].x, eA[7].y);
    o[4] = make_float4(eB[0].x, eB[0].y, eB[1].x, eB[1].y);
    o[5] = make_float4(eB[2].x, eB[2].y, eB[3].x, eB[3].y);
    o[6] = make_float4(eB[4].x, eB[4].y, eB[5].x, eB[5].y);
    o[7] = make_float4(eB[6].x, eB[6].y, eB[7].x, eB[7].y);
}

// ---------------------------------------------------------------------------
// Fused column FFT + rings, v11: 512 threads / 8 waves / 8 mirror pairs per
// block -> 1024 blocks (was 2048 x 256). DIAGNOSTIC+WIN experiment: cols has
// been pinned at ~74 µs across occupancy x1.6 (r2), ILP x2 (r3), VALU -8%
// (r9) — all levers INSIDE the per-wave model. The never-varied quantity is
// block count / per-block fixed overhead (T-table build, bins zero+dump,
// barriers, launch ramp). Halving block count halves fixed costs; per-wave
// code is byte-identical. LDS 8x576 scratch + T + bins = 44.6 KB ->
// 3 blocks/CU = 24 waves/CU (same wave capacity as 6 x 4-wave blocks).
// Bonus: 1024 output slices -> finalize reads halve to 3.2 MB.
// ---------------------------------------------------------------------------
__global__ __launch_bounds__(512) void fft_cols_rings(const float2* __restrict__ Zt,
                                                      float* __restrict__ sums,
                                                      int big) {
    __shared__ float2 S[8 * 576];      // 36,864 B
    __shared__ float2 T[576];          //  4,608 B
    __shared__ float  bins[258 * 3];   //  3,096 B
    const int t = threadIdx.x, w = t >> 6, J = t & 63;
    const int im = blockIdx.x >> 5, g = blockIdx.x & 31;    // 32 imgs x 32 grps
    const int p = 8 * g + w;                                // mirror pair 0..255

    {
        float s, c;
        __sincosf(-2.0f * PI_F * (float)t / 512.0f, &s, &c);
        T[t + (t >> 3)] = make_float2(c, s);
    }
    for (int i = t; i < 258 * 3; i += 512) bins[i] = 0.0f;

    const int c0 = (p == 0) ? 0   : p;
    const int c1 = (p == 0) ? 256 : 512 - p;
    const float2* rp0 = Zt + ((size_t)im << 18) + ((size_t)c0 << 9);
    const float2* rp1 = Zt + ((size_t)im << 18) + ((size_t)c1 << 9);
    float2 X0[8], X1[8];
#pragma unroll
    for (int q = 0; q < 8; ++q) { X0[q] = rp0[J + 64*q]; X1[q] = rp1[J + 64*q]; }
    __syncthreads();                       // T ready, bins zeroed

    float2* A = S + w * 576;               // single wave-private region
    const int r  = ((J & 7) << 3) | (J >> 3);
    const int pk = r + (r >> 3);           // sw(64k + r) = 72k + pk

    const float scale = 1.0f / (512.0f * 512.0f);
    auto pix = [&](float2 zk, float2 zm, float& av, float& c1v, float& c2v) {
        float f1r = 0.5f * (zk.x + zm.x) * scale;
        float f1i = 0.5f * (zk.y - zm.y) * scale;
        float f2r = 0.5f * (zk.y + zm.y) * scale;
        float f2i = 0.5f * (zm.x - zk.x) * scale;
        av  = f1r * f2r + f1i * f2i;
        c1v = f1r * f1r + f1i * f1i;
        c2v = f2r * f2r + f2i * f2i;
    };
    auto flush = [&](int ring, float a, float b, float c) {
        if (ring >= 0 && ring <= 256) {
            unsafeAtomicAdd(&bins[ring*3+0], a);
            unsafeAtomicAdd(&bins[ring*3+1], b);
            unsafeAtomicAdd(&bins[ring*3+2], c);
        }
    };

    wave_fft512_dual(X0, X1, A, T, J);

#pragma unroll
    for (int k = 0; k < 8; ++k) A[72*k + pk] = X0[k];

    float2 asv[8];
    if (p == 0) {
        int cur0 = -1;
        float a0 = 0, b0 = 0, c0v = 0;
#pragma unroll
        for (int i = 0; i < 8; ++i) {
            const int ky  = 8*J + i;
            const int kyp = (512 - ky) & 511;
            float2 zk = A[sw(ky)], zm = A[sw(kyp)];
            const float fk = (ky < 256) ? (float)ky : (float)(ky - 512);
            float av, cv, dv;
            pix(zk, zm, av, cv, dv);                       // col 0, fy = 0
            int rr = (int)rintf(fabsf(fk)); if (rr > 256) rr = 257;
            if (rr != cur0) { flush(cur0, a0, b0, c0v); cur0 = rr; a0 = av; b0 = cv; c0v = dv; }
            else            { a0 += av; b0 += cv; c0v += dv; }
        }
        flush(cur0, a0, b0, c0v);
    } else {
#pragma unroll
        for (int i = 0; i < 8; ++i) asv[i] = A[9*J + i];
    }

#pragma unroll
    for (int k = 0; k < 8; ++k) A[72*k + pk] = X1[k];

    if (p == 0) {
        int cur1 = -1;
        float a1 = 0, b1 = 0, c1v = 0;
#pragma unroll
        for (int i = 0; i < 8; ++i) {
            const int ky  = 8*J + i;
            const int kyp = (512 - ky) & 511;
            float2 zk = A[sw(ky)], zm = A[sw(kyp)];
            const float fk = (ky < 256) ? (float)ky : (float)(ky - 512);
            float av, cv, dv;
            pix(zk, zm, av, cv, dv);                       // col 256, fy = 256
            int rr = (int)rintf(sqrtf(fk*fk + 65536.0f)); if (rr > 256) rr = 257;
            if (rr != cur1) { flush(cur1, a1, b1, c1v); cur1 = rr; a1 = av; b1 = cv; c1v = dv; }
            else            { a1 += av; b1 += cv; c1v += dv; }
        }
        flush(cur1, a1, b1, c1v);
    } else {
        const float fy2 = (float)p * (float)p;
        int curR = -1;
        float sA = 0, sB = 0, sC = 0;
#pragma unroll
        for (int i = 0; i < 8; ++i) {
            const int ky  = 8*J + i;
            const int kyp = (512 - ky) & 511;
            float2 zk = asv[i];              // P0[ky]
            float2 zm = A[sw(kyp)];          // P1[512-ky]
            float a1v, b1v, d1v;
            pix(zk, zm, a1v, b1v, d1v);
            // Hermitian: mirror pixel (512-p, 512-ky) has identical a,c1,c2.
            const float fk = (ky < 256) ? (float)ky : (float)(ky - 512);
            int rr = (int)rintf(sqrtf(fk*fk + fy2)); if (rr > 256) rr = 257;
            const float aa = 2.0f*a1v, bb = 2.0f*b1v, cc = 2.0f*d1v;
            if (rr != curR) { flush(curR, sA, sB, sC); curR = rr; sA = aa; sB = bb; sC = cc; }
            else            { sA += aa; sB += bb; sC += cc; }
        }
        flush(curR, sA, sB, sC);
    }
    __syncthreads();

    // ---- bin dump (plain stores, private slice per block)
    if (big) {
        float* dst = sums + (size_t)blockIdx.x * NB3;          // private slice
        for (int i = t; i < NB3; i += 512) dst[i] = bins[i];
    } else {
        float* dst = sums + (size_t)(im * 8 + (g & 7)) * NB3;  // shared slice
        for (int i = t; i < NB3; i += 512) unsafeAtomicAdd(&dst[i], bins[i]);
    }
}

// ---------------------------------------------------------------------------
// Finalize, standalone: block = image; compile-time-unrolled slice loop
// (runtime spi was r3's ~50 µs mistake — serial dependent-load chain).
// ---------------------------------------------------------------------------
__global__ __launch_bounds__(256) void finalize(const float* __restrict__ sums,
                                                float* __restrict__ out, int spi) {
    const int im = blockIdx.x, t = threadIdx.x;
    const float* base = sums + (size_t)im * spi * NB3;
    float acc = 0.0f;
    for (int rr = t; rr < 257; rr += 256) {
        float cr = 0.f, c1s = 0.f, c2s = 0.f;
        if (spi == 32) {
#pragma unroll
            for (int s = 0; s < 32; ++s) {
                const float* pp = base + (size_t)s * NB3 + rr * 3;
                cr += pp[0]; c1s += pp[1]; c2s += pp[2];
            }
        } else {
            for (int s = 0; s < spi; ++s) {
                const float* pp = base + (size_t)s * NB3 + rr * 3;
                cr += pp[0]; c1s += pp[1]; c2s += pp[2];
            }
        }
        float frc = fabsf(cr) / (sqrtf(c1s * c2s) + 1e-8f);
        float d = 1.0f - frc;
        acc += d * d;
    }
#pragma unroll
    for (int off = 32; off > 0; off >>= 1) acc += __shfl_down(acc, off);
    __shared__ float red[4];
    if ((t & 63) == 0) red[t >> 6] = acc;
    __syncthreads();
    if (t == 0)
        unsafeAtomicAdd(out, (red[0] + red[1] + red[2] + red[3]) *
                             (1.0f / (257.0f * (float)NIMG)));
}

// ---------------------------------------------------------------------------
extern "C" void kernel_launch(void* const* d_in, const int* in_sizes, int n_in,
                              void* d_out, int out_size, void* d_ws, size_t ws_size,
                              hipStream_t stream) {
    const float* xr = (const float*)d_in[0];   // output: 32x1x512x512 f32
    const float* yr = (const float*)d_in[1];   // target: 32x1x512x512 f32

    float2* Zt = (float2*)d_ws;                                    // 64 MiB
    const size_t ztBytes = ((size_t)NIMG << 18) * sizeof(float2);
    float* sums = (float*)((char*)d_ws + ztBytes);
    const int big = (ws_size >= ztBytes + (size_t)1024 * NB3 * sizeof(float)) ? 1 : 0;

    // 3 nodes, no memsets: rows zeroes out[0] (+ slices in !big);
    // cols is pure FFT+rings+dump (1024 x 512); finalize reduces and writes.
    fft_rows_T    <<<dim3(NIMG * 32), dim3(512), 0, stream>>>(xr, yr, Zt, sums, (float*)d_out, big);
    fft_cols_rings<<<dim3(NIMG * 32), dim3(512), 0, stream>>>(Zt, sums, big);
    finalize      <<<dim3(NIMG), dim3(256), 0, stream>>>(sums, (float*)d_out, big ? 32 : 8);
}

// Round 11
// 187.710 us; speedup vs baseline: 1.0145x; 1.0145x over previous
//
#include <hip/hip_runtime.h>
#include <math.h>

#define NIMG 32
#define NB3  771             // 257 rings * 3 sums
#define NSLICE (NIMG * 8)    // fallback: 8 shared slices per image
#define PI_F 3.14159265358979323846f

// ---------------------------------------------------------------------------
__device__ __forceinline__ float2 cadd(float2 a, float2 b){ return make_float2(a.x+b.x, a.y+b.y); }
__device__ __forceinline__ float2 csub(float2 a, float2 b){ return make_float2(a.x-b.x, a.y-b.y); }
__device__ __forceinline__ float2 cmul(float2 a, float2 b){ return make_float2(a.x*b.x - a.y*b.y, a.x*b.y + a.y*b.x); }
__device__ __forceinline__ float2 cmul_mi(float2 a){ return make_float2(a.y, -a.x); }   // * (-i)
__device__ __forceinline__ float2 tw(const float2* T, int m){ return T[m + (m >> 3)]; }
__device__ __forceinline__ int   sw(int pos){ return pos + (pos >> 3); }     // LDS pad swizzle

// 8-point DFT (DIF, natural-order outputs), e^{-2pi i/8} convention
__device__ __forceinline__ void dft8(float2* x) {
    const float c = 0.70710678118654752f;
    float2 u0 = cadd(x[0], x[4]), u1 = cadd(x[1], x[5]);
    float2 u2 = cadd(x[2], x[6]), u3 = cadd(x[3], x[7]);
    float2 v0 = csub(x[0], x[4]);
    float2 d1 = csub(x[1], x[5]);
    float2 v1 = make_float2(c*(d1.x + d1.y), c*(d1.y - d1.x));
    float2 d2 = csub(x[2], x[6]);
    float2 v2 = make_float2(d2.y, -d2.x);
    float2 d3 = csub(x[3], x[7]);
    float2 v3 = make_float2(-c*(d3.x - d3.y), -c*(d3.x + d3.y));
    float2 e0 = cadd(u0,u2), e1 = cadd(u1,u3);
    float2 f0 = csub(u0,u2), f1 = cmul_mi(csub(u1,u3));
    float2 g0 = cadd(v0,v2), g1 = cadd(v1,v3);
    float2 h0 = csub(v0,v2), h1 = cmul_mi(csub(v1,v3));
    x[0] = cadd(e0,e1); x[4] = csub(e0,e1);
    x[2] = cadd(f0,f1); x[6] = csub(f0,f1);
    x[1] = cadd(g0,g1); x[5] = csub(g0,g1);
    x[3] = cadd(h0,h1); x[7] = csub(h0,h1);
}

// ---------------------------------------------------------------------------
// DUAL per-wave 512-pt radix-8 DIF FFT: two independent chains interleaved,
// sharing one 576-slot wave-private scratch (in-order LDS pipe makes the
// readA-before-writeB overlap safe). Thread J enters with X[q] = x[J+64q],
// exits with X[k] = F(64k + r), r = 8*(J&7) + (J>>3).
// ---------------------------------------------------------------------------
__device__ __forceinline__ void wave_fft512_dual(float2* Xa, float2* Xb,
                                                 float2* Sw, const float2* T,
                                                 int J) {
    dft8(Xa);
    dft8(Xb);
#pragma unroll
    for (int k = 1; k < 8; ++k) Xa[k] = cmul(Xa[k], tw(T, J * k));
#pragma unroll
    for (int k = 1; k < 8; ++k) Xb[k] = cmul(Xb[k], tw(T, J * k));
    const int jj = J + (J >> 3);
    const int j2 = J & 7;
    const int bb = 72 * (J >> 3) + j2;

#pragma unroll
    for (int k = 0; k < 8; ++k) Sw[jj + 72*k] = Xa[k];
#pragma unroll
    for (int q = 0; q < 8; ++q) Xa[q] = Sw[bb + 9*q];
#pragma unroll
    for (int k = 0; k < 8; ++k) Sw[jj + 72*k] = Xb[k];
#pragma unroll
    for (int q = 0; q < 8; ++q) Xb[q] = Sw[bb + 9*q];

    dft8(Xa);
    dft8(Xb);
#pragma unroll
    for (int k = 1; k < 8; ++k) Xa[k] = cmul(Xa[k], tw(T, 8 * j2 * k));
#pragma unroll
    for (int k = 1; k < 8; ++k) Xb[k] = cmul(Xb[k], tw(T, 8 * j2 * k));

#pragma unroll
    for (int k = 0; k < 8; ++k) Sw[bb + 9*k] = Xa[k];
#pragma unroll
    for (int q = 0; q < 8; ++q) Xa[q] = Sw[9*J + q];
#pragma unroll
    for (int k = 0; k < 8; ++k) Sw[bb + 9*k] = Xb[k];
#pragma unroll
    for (int q = 0; q < 8; ++q) Xb[q] = Sw[9*J + q];

    dft8(Xa);
    dft8(Xb);
}

// ---------------------------------------------------------------------------
// Row pass (r5 structure, unchanged): 512 threads / 16 image-rows per block,
// Zt[im][kx][y], ONE contiguous 128 B line per thread. Zeroes out[0] (block
// 0 — race-free vs finalize: stream-ordered) and, in the !big fallback, the
// shared slices.
// ---------------------------------------------------------------------------
__global__ __launch_bounds__(512) void fft_rows_T(const float* __restrict__ xr,
                                                  const float* __restrict__ yr,
                                                  float2* __restrict__ Zt,
                                                  float* __restrict__ sums,
                                                  float* __restrict__ out,
                                                  int big) {
    __shared__ float2 S[8 * 576];      // 36,864 B (wave scratch + park)
    __shared__ float2 T[576];          //  4,608 B
    const int t = threadIdx.x, w = t >> 6, J = t & 63;
    const int im = blockIdx.x >> 5, grp = blockIdx.x & 31;   // 32 imgs x 32 grps

    if (!big && blockIdx.x < NSLICE) {
        float* z = sums + (size_t)blockIdx.x * NB3;
        for (int i = t; i < NB3; i += 512) z[i] = 0.0f;
    }
    if (blockIdx.x == 0 && t == 0) out[0] = 0.0f;

    {
        float s, c;
        __sincosf(-2.0f * PI_F * (float)t / 512.0f, &s, &c);
        T[t + (t >> 3)] = make_float2(c, s);
    }

    // wave w: rowA = grp*16 + w, rowB = grp*16 + 8 + w
    const size_t b0 = ((size_t)(im * 512 + grp * 16 + w)) << 9;
    const size_t b1 = b0 + ((size_t)8 << 9);
    float2 X0[8], X1[8];
#pragma unroll
    for (int q = 0; q < 8; ++q) {
        X0[q] = make_float2(xr[b0 + J + 64*q], yr[b0 + J + 64*q]);
        X1[q] = make_float2(xr[b1 + J + 64*q], yr[b1 + J + 64*q]);
    }
    __syncthreads();                       // T ready

    float2* Sw = S + w * 576;
    wave_fft512_dual(X0, X1, Sw, T, J);

    const int r = ((J & 7) << 3) | (J >> 3);

    // park X0 (rows y0..y0+7, one per wave) -> gather 8 y's per kx
#pragma unroll
    for (int k = 0; k < 8; ++k) Sw[64*k + r] = X0[k];
    __syncthreads();
    float2 eA[8];
#pragma unroll
    for (int j = 0; j < 8; ++j) eA[j] = S[j*576 + t];   // F_row(y0+j)(kx=t)
    __syncthreads();

    // park X1 (rows y0+8..y0+15)
#pragma unroll
    for (int k = 0; k < 8; ++k) Sw[64*k + r] = X1[k];
    __syncthreads();
    float2 eB[8];
#pragma unroll
    for (int j = 0; j < 8; ++j) eB[j] = S[j*576 + t];   // F_row(y0+8+j)(kx=t)

    // one full 128 B line per thread: Zt[im][t][grp*16 .. grp*16+15]
    float4* o = (float4*)(Zt + ((size_t)im << 18) + ((size_t)t << 9)
                             + (size_t)(grp * 16));
    o[0] = make_float4(eA[0].x, eA[0].y, eA[1].x, eA[1].y);
    o[1] = make_float4(eA[2].x, eA[2].y, eA[3].x, eA[3].y);
    o[2] = make_float4(eA[4].x, eA[4].y, eA[5].x, eA[5].y);
    o[3] = make_float4(eA[6].x, eA[6].y, eA[7].x, eA[7].y);
    o[4] = make_float4(eB[0].x, eB[0].y, eB[1].x, eB[1].y);
    o[5] = make_float4(eB[2].x, eB[2].y, eB[3].x, eB[3].y);
    o[6] = make_float4(eB[4].x, eB[4].y, eB[5].x, eB[5].y);
    o[7] = make_float4(eB[6].x, eB[6].y, eB[7].x, eB[7].y);
}

// ---------------------------------------------------------------------------
// Fused column FFT + rings (exact r9 winner: 2048 blocks x 256 threads,
// contiguous loads, Hermitian pix-halving, plain-store private slices, no
// in-kernel finalize). Cols is invariant at ~74 µs across occupancy x1.6,
// ILP x2, VALU -8%, block count x0.5 — left untouched this round.
// ---------------------------------------------------------------------------
__global__ __launch_bounds__(256) void fft_cols_rings(const float2* __restrict__ Zt,
                                                      float* __restrict__ sums,
                                                      int big) {
    __shared__ float2 S[4 * 576];      // 18,432 B
    __shared__ float2 T[576];          //  4,608 B
    __shared__ float  bins[258 * 3];   //  3,096 B
    const int t = threadIdx.x, w = t >> 6, J = t & 63;
    const int im = blockIdx.x >> 6, g = blockIdx.x & 63;
    const int p = 4 * g + w;

#pragma unroll
    for (int i = 0; i < 2; ++i) {
        const int m = t + 256 * i;
        float s, c;
        __sincosf(-2.0f * PI_F * (float)m / 512.0f, &s, &c);
        T[m + (m >> 3)] = make_float2(c, s);
    }
    for (int i = t; i < 258 * 3; i += 256) bins[i] = 0.0f;

    const int c0 = (p == 0) ? 0   : p;
    const int c1 = (p == 0) ? 256 : 512 - p;
    const float2* rp0 = Zt + ((size_t)im << 18) + ((size_t)c0 << 9);
    const float2* rp1 = Zt + ((size_t)im << 18) + ((size_t)c1 << 9);
    float2 X0[8], X1[8];
#pragma unroll
    for (int q = 0; q < 8; ++q) { X0[q] = rp0[J + 64*q]; X1[q] = rp1[J + 64*q]; }
    __syncthreads();                       // T ready, bins zeroed

    float2* A = S + w * 576;               // single wave-private region
    const int r  = ((J & 7) << 3) | (J >> 3);
    const int pk = r + (r >> 3);           // sw(64k + r) = 72k + pk

    const float scale = 1.0f / (512.0f * 512.0f);
    auto pix = [&](float2 zk, float2 zm, float& av, float& c1v, float& c2v) {
        float f1r = 0.5f * (zk.x + zm.x) * scale;
        float f1i = 0.5f * (zk.y - zm.y) * scale;
        float f2r = 0.5f * (zk.y + zm.y) * scale;
        float f2i = 0.5f * (zm.x - zk.x) * scale;
        av  = f1r * f2r + f1i * f2i;
        c1v = f1r * f1r + f1i * f1i;
        c2v = f2r * f2r + f2i * f2i;
    };
    auto flush = [&](int ring, float a, float b, float c) {
        if (ring >= 0 && ring <= 256) {
            unsafeAtomicAdd(&bins[ring*3+0], a);
            unsafeAtomicAdd(&bins[ring*3+1], b);
            unsafeAtomicAdd(&bins[ring*3+2], c);
        }
    };

    wave_fft512_dual(X0, X1, A, T, J);

#pragma unroll
    for (int k = 0; k < 8; ++k) A[72*k + pk] = X0[k];

    float2 asv[8];
    if (p == 0) {
        int cur0 = -1;
        float a0 = 0, b0 = 0, c0v = 0;
#pragma unroll
        for (int i = 0; i < 8; ++i) {
            const int ky  = 8*J + i;
            const int kyp = (512 - ky) & 511;
            float2 zk = A[sw(ky)], zm = A[sw(kyp)];
            const float fk = (ky < 256) ? (float)ky : (float)(ky - 512);
            float av, cv, dv;
            pix(zk, zm, av, cv, dv);                       // col 0, fy = 0
            int rr = (int)rintf(fabsf(fk)); if (rr > 256) rr = 257;
            if (rr != cur0) { flush(cur0, a0, b0, c0v); cur0 = rr; a0 = av; b0 = cv; c0v = dv; }
            else            { a0 += av; b0 += cv; c0v += dv; }
        }
        flush(cur0, a0, b0, c0v);
    } else {
#pragma unroll
        for (int i = 0; i < 8; ++i) asv[i] = A[9*J + i];
    }

#pragma unroll
    for (int k = 0; k < 8; ++k) A[72*k + pk] = X1[k];

    if (p == 0) {
        int cur1 = -1;
        float a1 = 0, b1 = 0, c1v = 0;
#pragma unroll
        for (int i = 0; i < 8; ++i) {
            const int ky  = 8*J + i;
            const int kyp = (512 - ky) & 511;
            float2 zk = A[sw(ky)], zm = A[sw(kyp)];
            const float fk = (ky < 256) ? (float)ky : (float)(ky - 512);
            float av, cv, dv;
            pix(zk, zm, av, cv, dv);                       // col 256, fy = 256
            int rr = (int)rintf(sqrtf(fk*fk + 65536.0f)); if (rr > 256) rr = 257;
            if (rr != cur1) { flush(cur1, a1, b1, c1v); cur1 = rr; a1 = av; b1 = cv; c1v = dv; }
            else            { a1 += av; b1 += cv; c1v += dv; }
        }
        flush(cur1, a1, b1, c1v);
    } else {
        const float fy2 = (float)p * (float)p;
        int curR = -1;
        float sA = 0, sB = 0, sC = 0;
#pragma unroll
        for (int i = 0; i < 8; ++i) {
            const int ky  = 8*J + i;
            const int kyp = (512 - ky) & 511;
            float2 zk = asv[i];              // P0[ky]
            float2 zm = A[sw(kyp)];          // P1[512-ky]
            float a1v, b1v, d1v;
            pix(zk, zm, a1v, b1v, d1v);
            // Hermitian: mirror pixel (512-p, 512-ky) has identical a,c1,c2.
            const float fk = (ky < 256) ? (float)ky : (float)(ky - 512);
            int rr = (int)rintf(sqrtf(fk*fk + fy2)); if (rr > 256) rr = 257;
            const float aa = 2.0f*a1v, bb = 2.0f*b1v, cc = 2.0f*d1v;
            if (rr != curR) { flush(curR, sA, sB, sC); curR = rr; sA = aa; sB = bb; sC = cc; }
            else            { sA += aa; sB += bb; sC += cc; }
        }
        flush(curR, sA, sB, sC);
    }
    __syncthreads();

    // ---- bin dump (plain stores, private slice per block)
    if (big) {
        float* dst = sums + (size_t)blockIdx.x * NB3;          // private slice
        for (int i = t; i < NB3; i += 256) dst[i] = bins[i];
    } else {
        float* dst = sums + (size_t)(im * 8 + (g & 7)) * NB3;  // shared slice
        for (int i = t; i < NB3; i += 256) unsafeAtomicAdd(&dst[i], bins[i]);
    }
}

// ---------------------------------------------------------------------------
// Finalize v2 — FULLY PARALLEL. r9's 32-block version was never directly
// observed; budget arithmetic (total 185 = rows<73 + cols~75 + X) shows
// X = finalize+gaps >= 37 µs. Old shape: 32 blocks (12.5% of GPU), thread-
// serial 64-slice walk — the same latency-bound shape as the r3-era ~50 µs
// finalize. New shape: grid = 257 blocks (one per ring) x 512 threads;
// thread (im = t>>4, sl = t&15) strides slices; 16-lane shuffle reduce per
// image; per-image d^2 -> LDS; 32-lane reduce; ONE atomicAdd per block.
// TLP: 2056 waves (vs 128), MLP ~12 loads/thread. All reads L2/L3-resident.
// ---------------------------------------------------------------------------
__global__ __launch_bounds__(512) void finalize(const float* __restrict__ sums,
                                                float* __restrict__ out, int spi) {
    const int rr = blockIdx.x;             // ring 0..256
    const int t  = threadIdx.x;
    const int im = t >> 4, sl = t & 15;
    float cr = 0.f, c1s = 0.f, c2s = 0.f;
    const float* base = sums + (size_t)im * spi * NB3 + rr * 3;
    for (int s = sl; s < spi; s += 16) {
        const float* pp = base + (size_t)s * NB3;
        cr += pp[0]; c1s += pp[1]; c2s += pp[2];
    }
    // reduce across the 16 lanes of this image (lane groups of 16 within wave)
#pragma unroll
    for (int off = 8; off > 0; off >>= 1) {
        cr  += __shfl_down(cr,  off, 16);
        c1s += __shfl_down(c1s, off, 16);
        c2s += __shfl_down(c2s, off, 16);
    }
    __shared__ float red[32];
    if (sl == 0) {
        float frc = fabsf(cr) / (sqrtf(c1s * c2s) + 1e-8f);
        float d = 1.0f - frc;
        red[im] = d * d;
    }
    __syncthreads();
    if (t < 32) {
        float v = red[t];
#pragma unroll
        for (int off = 16; off > 0; off >>= 1) v += __shfl_down(v, off, 32);
        if (t == 0)
            unsafeAtomicAdd(out, v * (1.0f / (257.0f * (float)NIMG)));
    }
}

// ---------------------------------------------------------------------------
extern "C" void kernel_launch(void* const* d_in, const int* in_sizes, int n_in,
                              void* d_out, int out_size, void* d_ws, size_t ws_size,
                              hipStream_t stream) {
    const float* xr = (const float*)d_in[0];   // output: 32x1x512x512 f32
    const float* yr = (const float*)d_in[1];   // target: 32x1x512x512 f32

    float2* Zt = (float2*)d_ws;                                    // 64 MiB
    const size_t ztBytes = ((size_t)NIMG << 18) * sizeof(float2);
    float* sums = (float*)((char*)d_ws + ztBytes);
    const int big = (ws_size >= ztBytes + (size_t)2048 * NB3 * sizeof(float)) ? 1 : 0;

    // 3 nodes, no memsets: rows zeroes out[0] (+ slices in !big);
    // cols is pure FFT+rings+dump; finalize is one-ring-per-block parallel.
    fft_rows_T    <<<dim3(NIMG * 32), dim3(512), 0, stream>>>(xr, yr, Zt, sums, (float*)d_out, big);
    fft_cols_rings<<<dim3(NIMG * 64), dim3(256), 0, stream>>>(Zt, sums, big);
    finalize      <<<dim3(257), dim3(512), 0, stream>>>(sums, (float*)d_out, big ? 64 : 8);
}

// Round 12
// 183.979 us; speedup vs baseline: 1.0351x; 1.0203x over previous
//
#include <hip/hip_runtime.h>
#include <math.h>

#define NIMG 32
#define NB3  771             // 257 rings * 3 sums
#define NSLICE (NIMG * 8)    // fallback: 8 shared slices per image
#define PI_F 3.14159265358979323846f

// ---------------------------------------------------------------------------
__device__ __forceinline__ float2 cadd(float2 a, float2 b){ return make_float2(a.x+b.x, a.y+b.y); }
__device__ __forceinline__ float2 csub(float2 a, float2 b){ return make_float2(a.x-b.x, a.y-b.y); }
__device__ __forceinline__ float2 cmul(float2 a, float2 b){ return make_float2(a.x*b.x - a.y*b.y, a.x*b.y + a.y*b.x); }
__device__ __forceinline__ float2 cmul_mi(float2 a){ return make_float2(a.y, -a.x); }   // * (-i)
__device__ __forceinline__ float2 tw(const float2* T, int m){ return T[m + (m >> 3)]; }
__device__ __forceinline__ int   sw(int pos){ return pos + (pos >> 3); }     // LDS pad swizzle

// 8-point DFT (DIF, natural-order outputs), e^{-2pi i/8} convention
__device__ __forceinline__ void dft8(float2* x) {
    const float c = 0.70710678118654752f;
    float2 u0 = cadd(x[0], x[4]), u1 = cadd(x[1], x[5]);
    float2 u2 = cadd(x[2], x[6]), u3 = cadd(x[3], x[7]);
    float2 v0 = csub(x[0], x[4]);
    float2 d1 = csub(x[1], x[5]);
    float2 v1 = make_float2(c*(d1.x + d1.y), c*(d1.y - d1.x));
    float2 d2 = csub(x[2], x[6]);
    float2 v2 = make_float2(d2.y, -d2.x);
    float2 d3 = csub(x[3], x[7]);
    float2 v3 = make_float2(-c*(d3.x - d3.y), -c*(d3.x + d3.y));
    float2 e0 = cadd(u0,u2), e1 = cadd(u1,u3);
    float2 f0 = csub(u0,u2), f1 = cmul_mi(csub(u1,u3));
    float2 g0 = cadd(v0,v2), g1 = cadd(v1,v3);
    float2 h0 = csub(v0,v2), h1 = cmul_mi(csub(v1,v3));
    x[0] = cadd(e0,e1); x[4] = csub(e0,e1);
    x[2] = cadd(f0,f1); x[6] = csub(f0,f1);
    x[1] = cadd(g0,g1); x[5] = csub(g0,g1);
    x[3] = cadd(h0,h1); x[7] = csub(h0,h1);
}

// ---------------------------------------------------------------------------
// DUAL per-wave 512-pt radix-8 DIF FFT: two independent chains interleaved,
// sharing one 576-slot wave-private scratch (in-order LDS pipe makes the
// readA-before-writeB overlap safe). Thread J enters with X[q] = x[J+64q],
// exits with X[k] = F(64k + r), r = 8*(J&7) + (J>>3).
// r12: callers wrap this in s_setprio(1)/(0) — T5: waves in this dependent-
// latency chain get issue preference over co-resident waves doing ring
// atomics / slice dumps (wave role diversity exists: no barriers between
// the two block syncs, 24 waves/CU drift across phases independently).
// ---------------------------------------------------------------------------
__device__ __forceinline__ void wave_fft512_dual(float2* Xa, float2* Xb,
                                                 float2* Sw, const float2* T,
                                                 int J) {
    dft8(Xa);
    dft8(Xb);
#pragma unroll
    for (int k = 1; k < 8; ++k) Xa[k] = cmul(Xa[k], tw(T, J * k));
#pragma unroll
    for (int k = 1; k < 8; ++k) Xb[k] = cmul(Xb[k], tw(T, J * k));
    const int jj = J + (J >> 3);
    const int j2 = J & 7;
    const int bb = 72 * (J >> 3) + j2;

#pragma unroll
    for (int k = 0; k < 8; ++k) Sw[jj + 72*k] = Xa[k];
#pragma unroll
    for (int q = 0; q < 8; ++q) Xa[q] = Sw[bb + 9*q];
#pragma unroll
    for (int k = 0; k < 8; ++k) Sw[jj + 72*k] = Xb[k];
#pragma unroll
    for (int q = 0; q < 8; ++q) Xb[q] = Sw[bb + 9*q];

    dft8(Xa);
    dft8(Xb);
#pragma unroll
    for (int k = 1; k < 8; ++k) Xa[k] = cmul(Xa[k], tw(T, 8 * j2 * k));
#pragma unroll
    for (int k = 1; k < 8; ++k) Xb[k] = cmul(Xb[k], tw(T, 8 * j2 * k));

#pragma unroll
    for (int k = 0; k < 8; ++k) Sw[bb + 9*k] = Xa[k];
#pragma unroll
    for (int q = 0; q < 8; ++q) Xa[q] = Sw[9*J + q];
#pragma unroll
    for (int k = 0; k < 8; ++k) Sw[bb + 9*k] = Xb[k];
#pragma unroll
    for (int q = 0; q < 8; ++q) Xb[q] = Sw[9*J + q];

    dft8(Xa);
    dft8(Xb);
}

// ---------------------------------------------------------------------------
// Row pass (r5 structure): 512 threads / 16 image-rows per block,
// Zt[im][kx][y], ONE contiguous 128 B line per thread. Zeroes out[0] and,
// in the !big fallback, the shared slices.
// ---------------------------------------------------------------------------
__global__ __launch_bounds__(512) void fft_rows_T(const float* __restrict__ xr,
                                                  const float* __restrict__ yr,
                                                  float2* __restrict__ Zt,
                                                  float* __restrict__ sums,
                                                  float* __restrict__ out,
                                                  int big) {
    __shared__ float2 S[8 * 576];      // 36,864 B (wave scratch + park)
    __shared__ float2 T[576];          //  4,608 B
    const int t = threadIdx.x, w = t >> 6, J = t & 63;
    const int im = blockIdx.x >> 5, grp = blockIdx.x & 31;   // 32 imgs x 32 grps

    if (!big && blockIdx.x < NSLICE) {
        float* z = sums + (size_t)blockIdx.x * NB3;
        for (int i = t; i < NB3; i += 512) z[i] = 0.0f;
    }
    if (blockIdx.x == 0 && t == 0) out[0] = 0.0f;

    {
        float s, c;
        __sincosf(-2.0f * PI_F * (float)t / 512.0f, &s, &c);
        T[t + (t >> 3)] = make_float2(c, s);
    }

    // wave w: rowA = grp*16 + w, rowB = grp*16 + 8 + w
    const size_t b0 = ((size_t)(im * 512 + grp * 16 + w)) << 9;
    const size_t b1 = b0 + ((size_t)8 << 9);
    float2 X0[8], X1[8];
#pragma unroll
    for (int q = 0; q < 8; ++q) {
        X0[q] = make_float2(xr[b0 + J + 64*q], yr[b0 + J + 64*q]);
        X1[q] = make_float2(xr[b1 + J + 64*q], yr[b1 + J + 64*q]);
    }
    __syncthreads();                       // T ready

    float2* Sw = S + w * 576;
    __builtin_amdgcn_s_setprio(1);         // T5: favor the FFT dependent chain
    wave_fft512_dual(X0, X1, Sw, T, J);
    __builtin_amdgcn_s_setprio(0);

    const int r = ((J & 7) << 3) | (J >> 3);

    // park X0 (rows y0..y0+7, one per wave) -> gather 8 y's per kx
#pragma unroll
    for (int k = 0; k < 8; ++k) Sw[64*k + r] = X0[k];
    __syncthreads();
    float2 eA[8];
#pragma unroll
    for (int j = 0; j < 8; ++j) eA[j] = S[j*576 + t];   // F_row(y0+j)(kx=t)
    __syncthreads();

    // park X1 (rows y0+8..y0+15)
#pragma unroll
    for (int k = 0; k < 8; ++k) Sw[64*k + r] = X1[k];
    __syncthreads();
    float2 eB[8];
#pragma unroll
    for (int j = 0; j < 8; ++j) eB[j] = S[j*576 + t];   // F_row(y0+8+j)(kx=t)

    // one full 128 B line per thread: Zt[im][t][grp*16 .. grp*16+15]
    float4* o = (float4*)(Zt + ((size_t)im << 18) + ((size_t)t << 9)
                             + (size_t)(grp * 16));
    o[0] = make_float4(eA[0].x, eA[0].y, eA[1].x, eA[1].y);
    o[1] = make_float4(eA[2].x, eA[2].y, eA[3].x, eA[3].y);
    o[2] = make_float4(eA[4].x, eA[4].y, eA[5].x, eA[5].y);
    o[3] = make_float4(eA[6].x, eA[6].y, eA[7].x, eA[7].y);
    o[4] = make_float4(eB[0].x, eB[0].y, eB[1].x, eB[1].y);
    o[5] = make_float4(eB[2].x, eB[2].y, eB[3].x, eB[3].y);
    o[6] = make_float4(eB[4].x, eB[4].y, eB[5].x, eB[5].y);
    o[7] = make_float4(eB[6].x, eB[6].y, eB[7].x, eB[7].y);
}

// ---------------------------------------------------------------------------
// Fused column FFT + rings (r9 winner: 2048 blocks x 256 threads, contiguous
// loads, Hermitian pix-halving, plain-store private slices, no in-kernel
// finalize) + T5 setprio around the FFT chain.
// ---------------------------------------------------------------------------
__global__ __launch_bounds__(256) void fft_cols_rings(const float2* __restrict__ Zt,
                                                      float* __restrict__ sums,
                                                      int big) {
    __shared__ float2 S[4 * 576];      // 18,432 B
    __shared__ float2 T[576];          //  4,608 B
    __shared__ float  bins[258 * 3];   //  3,096 B
    const int t = threadIdx.x, w = t >> 6, J = t & 63;
    const int im = blockIdx.x >> 6, g = blockIdx.x & 63;
    const int p = 4 * g + w;

#pragma unroll
    for (int i = 0; i < 2; ++i) {
        const int m = t + 256 * i;
        float s, c;
        __sincosf(-2.0f * PI_F * (float)m / 512.0f, &s, &c);
        T[m + (m >> 3)] = make_float2(c, s);
    }
    for (int i = t; i < 258 * 3; i += 256) bins[i] = 0.0f;

    const int c0 = (p == 0) ? 0   : p;
    const int c1 = (p == 0) ? 256 : 512 - p;
    const float2* rp0 = Zt + ((size_t)im << 18) + ((size_t)c0 << 9);
    const float2* rp1 = Zt + ((size_t)im << 18) + ((size_t)c1 << 9);
    float2 X0[8], X1[8];
#pragma unroll
    for (int q = 0; q < 8; ++q) { X0[q] = rp0[J + 64*q]; X1[q] = rp1[J + 64*q]; }
    __syncthreads();                       // T ready, bins zeroed

    float2* A = S + w * 576;               // single wave-private region
    const int r  = ((J & 7) << 3) | (J >> 3);
    const int pk = r + (r >> 3);           // sw(64k + r) = 72k + pk

    const float scale = 1.0f / (512.0f * 512.0f);
    auto pix = [&](float2 zk, float2 zm, float& av, float& c1v, float& c2v) {
        float f1r = 0.5f * (zk.x + zm.x) * scale;
        float f1i = 0.5f * (zk.y - zm.y) * scale;
        float f2r = 0.5f * (zk.y + zm.y) * scale;
        float f2i = 0.5f * (zm.x - zk.x) * scale;
        av  = f1r * f2r + f1i * f2i;
        c1v = f1r * f1r + f1i * f1i;
        c2v = f2r * f2r + f2i * f2i;
    };
    auto flush = [&](int ring, float a, float b, float c) {
        if (ring >= 0 && ring <= 256) {
            unsafeAtomicAdd(&bins[ring*3+0], a);
            unsafeAtomicAdd(&bins[ring*3+1], b);
            unsafeAtomicAdd(&bins[ring*3+2], c);
        }
    };

    __builtin_amdgcn_s_setprio(1);         // T5: favor the FFT dependent chain
    wave_fft512_dual(X0, X1, A, T, J);
    __builtin_amdgcn_s_setprio(0);

#pragma unroll
    for (int k = 0; k < 8; ++k) A[72*k + pk] = X0[k];

    float2 asv[8];
    if (p == 0) {
        int cur0 = -1;
        float a0 = 0, b0 = 0, c0v = 0;
#pragma unroll
        for (int i = 0; i < 8; ++i) {
            const int ky  = 8*J + i;
            const int kyp = (512 - ky) & 511;
            float2 zk = A[sw(ky)], zm = A[sw(kyp)];
            const float fk = (ky < 256) ? (float)ky : (float)(ky - 512);
            float av, cv, dv;
            pix(zk, zm, av, cv, dv);                       // col 0, fy = 0
            int rr = (int)rintf(fabsf(fk)); if (rr > 256) rr = 257;
            if (rr != cur0) { flush(cur0, a0, b0, c0v); cur0 = rr; a0 = av; b0 = cv; c0v = dv; }
            else            { a0 += av; b0 += cv; c0v += dv; }
        }
        flush(cur0, a0, b0, c0v);
    } else {
#pragma unroll
        for (int i = 0; i < 8; ++i) asv[i] = A[9*J + i];
    }

#pragma unroll
    for (int k = 0; k < 8; ++k) A[72*k + pk] = X1[k];

    if (p == 0) {
        int cur1 = -1;
        float a1 = 0, b1 = 0, c1v = 0;
#pragma unroll
        for (int i = 0; i < 8; ++i) {
            const int ky  = 8*J + i;
            const int kyp = (512 - ky) & 511;
            float2 zk = A[sw(ky)], zm = A[sw(kyp)];
            const float fk = (ky < 256) ? (float)ky : (float)(ky - 512);
            float av, cv, dv;
            pix(zk, zm, av, cv, dv);                       // col 256, fy = 256
            int rr = (int)rintf(sqrtf(fk*fk + 65536.0f)); if (rr > 256) rr = 257;
            if (rr != cur1) { flush(cur1, a1, b1, c1v); cur1 = rr; a1 = av; b1 = cv; c1v = dv; }
            else            { a1 += av; b1 += cv; c1v += dv; }
        }
        flush(cur1, a1, b1, c1v);
    } else {
        const float fy2 = (float)p * (float)p;
        int curR = -1;
        float sA = 0, sB = 0, sC = 0;
#pragma unroll
        for (int i = 0; i < 8; ++i) {
            const int ky  = 8*J + i;
            const int kyp = (512 - ky) & 511;
            float2 zk = asv[i];              // P0[ky]
            float2 zm = A[sw(kyp)];          // P1[512-ky]
            float a1v, b1v, d1v;
            pix(zk, zm, a1v, b1v, d1v);
            // Hermitian: mirror pixel (512-p, 512-ky) has identical a,c1,c2.
            const float fk = (ky < 256) ? (float)ky : (float)(ky - 512);
            int rr = (int)rintf(sqrtf(fk*fk + fy2)); if (rr > 256) rr = 257;
            const float aa = 2.0f*a1v, bb = 2.0f*b1v, cc = 2.0f*d1v;
            if (rr != curR) { flush(curR, sA, sB, sC); curR = rr; sA = aa; sB = bb; sC = cc; }
            else            { sA += aa; sB += bb; sC += cc; }
        }
        flush(curR, sA, sB, sC);
    }
    __syncthreads();

    // ---- bin dump (plain stores, private slice per block)
    if (big) {
        float* dst = sums + (size_t)blockIdx.x * NB3;          // private slice
        for (int i = t; i < NB3; i += 256) dst[i] = bins[i];
    } else {
        float* dst = sums + (size_t)(im * 8 + (g & 7)) * NB3;  // shared slice
        for (int i = t; i < NB3; i += 256) unsafeAtomicAdd(&dst[i], bins[i]);
    }
}

// ---------------------------------------------------------------------------
// Finalize (r9 version — measured best total): block = image; compile-time
// unrolled 64-slice reduction.
// ---------------------------------------------------------------------------
__global__ __launch_bounds__(256) void finalize(const float* __restrict__ sums,
                                                float* __restrict__ out, int spi) {
    const int im = blockIdx.x, t = threadIdx.x;
    const float* base = sums + (size_t)im * spi * NB3;
    float acc = 0.0f;
    for (int rr = t; rr < 257; rr += 256) {
        float cr = 0.f, c1s = 0.f, c2s = 0.f;
        if (spi == 64) {
#pragma unroll
            for (int s = 0; s < 64; ++s) {
                const float* pp = base + (size_t)s * NB3 + rr * 3;
                cr += pp[0]; c1s += pp[1]; c2s += pp[2];
            }
        } else {
            for (int s = 0; s < spi; ++s) {
                const float* pp = base + (size_t)s * NB3 + rr * 3;
                cr += pp[0]; c1s += pp[1]; c2s += pp[2];
            }
        }
        float frc = fabsf(cr) / (sqrtf(c1s * c2s) + 1e-8f);
        float d = 1.0f - frc;
        acc += d * d;
    }
#pragma unroll
    for (int off = 32; off > 0; off >>= 1) acc += __shfl_down(acc, off);
    __shared__ float red[4];
    if ((t & 63) == 0) red[t >> 6] = acc;
    __syncthreads();
    if (t == 0)
        unsafeAtomicAdd(out, (red[0] + red[1] + red[2] + red[3]) *
                             (1.0f / (257.0f * (float)NIMG)));
}

// ---------------------------------------------------------------------------
extern "C" void kernel_launch(void* const* d_in, const int* in_sizes, int n_in,
                              void* d_out, int out_size, void* d_ws, size_t ws_size,
                              hipStream_t stream) {
    const float* xr = (const float*)d_in[0];   // output: 32x1x512x512 f32
    const float* yr = (const float*)d_in[1];   // target: 32x1x512x512 f32

    float2* Zt = (float2*)d_ws;                                    // 64 MiB
    const size_t ztBytes = ((size_t)NIMG << 18) * sizeof(float2);
    float* sums = (float*)((char*)d_ws + ztBytes);
    const int big = (ws_size >= ztBytes + (size_t)2048 * NB3 * sizeof(float)) ? 1 : 0;

    // 3 nodes, no memsets: rows zeroes out[0] (+ slices in !big);
    // cols is pure FFT+rings+dump; finalize reduces slices and writes out.
    fft_rows_T    <<<dim3(NIMG * 32), dim3(512), 0, stream>>>(xr, yr, Zt, sums, (float*)d_out, big);
    fft_cols_rings<<<dim3(NIMG * 64), dim3(256), 0, stream>>>(Zt, sums, big);
    finalize      <<<dim3(NIMG), dim3(256), 0, stream>>>(sums, (float*)d_out, big ? 64 : 8);
}